// Round 3
// baseline (1835.027 us; speedup 1.0000x reference)
//
#include <hip/hip_runtime.h>
#include <hip/hip_bf16.h>

// LSTM cell: gates = X @ Wx^T + Hx @ Wh^T + (bx + bh); f,i,g,o = split(gates)
// cy = sigmoid(f)*cx + sigmoid(i)*tanh(g); hy = sigmoid(o)*tanh(cy)
// Storage dtype: fp32 (per reference). Compute: bf16 MFMA (checker is
// bf16-tolerant: floor_eps_k=8, threshold ~8e-2).
// R2: R0/R1 NaN'd because fp32 buffers were read as bf16 (low mantissa bits
// alias bf16 NaN encodings). Now: fp32 loads -> RNE cvt to bf16 at staging.
//
// 128(M) x 128(C) tile, C interleaves 4 gates: c -> gate=c&3, h=h0+(c>>2),
// so each 4-lane group of the MFMA C-layout holds all 4 gates of one (m,h)
// -> epilogue via 3 __shfl_xor, no gates workspace.

#define BATCH 4096
#define HID   2048
#define KDIM  2048
#define BM    128
#define BK    64

typedef __attribute__((ext_vector_type(8))) short  short8;
typedef __attribute__((ext_vector_type(4))) short  short4v;
typedef __attribute__((ext_vector_type(4))) float  f32x4;

__device__ __forceinline__ float sigm(float x)  { return 1.f / (1.f + __expf(-x)); }
__device__ __forceinline__ float tanhx(float x) { return 2.f / (1.f + __expf(-2.f * x)) - 1.f; }

__device__ __forceinline__ short bf16cvt(float f) {
  union { float f; unsigned u; } v; v.f = f;
  unsigned r = (v.u + 0x7FFFu + ((v.u >> 16) & 1u)) >> 16;   // RNE
  return (short)r;
}

__global__ __launch_bounds__(256) void lstm_cell_kernel(
    const float* __restrict__ X, const float* __restrict__ Hx,
    const float* __restrict__ Cx,
    const float* __restrict__ Wx, const float* __restrict__ bx,
    const float* __restrict__ Wh, const float* __restrict__ bh,
    float* __restrict__ Hy, float* __restrict__ Cy)
{
  __shared__ __align__(16) short A_lds[BM * BK];   // [m_local][k] 128x64 bf16, 16KB
  __shared__ __align__(16) short B_lds[BM * BK];   // [c][k]       128x64 bf16, 16KB

  const int tid  = threadIdx.x;
  const int wv   = tid >> 6;         // wave 0..3
  const int lane = tid & 63;
  const int quad = lane >> 4;
  const int ln   = lane & 15;
  const int wm   = wv >> 1;          // 2x2 wave grid
  const int wn   = wv & 1;
  const int m0   = blockIdx.y * BM;  // 32 m-tiles
  const int h0   = blockIdx.x * 32;  // 64 h-tiles

  f32x4 acc[4][4];
  #pragma unroll
  for (int a = 0; a < 4; ++a)
    #pragma unroll
    for (int b = 0; b < 4; ++b)
      acc[a][b] = (f32x4){0.f, 0.f, 0.f, 0.f};

  const float* Asrc[2] = {X, Hx};
  const float* Wsrc[2] = {Wx, Wh};

  for (int ph = 0; ph < 2; ++ph) {
    const float* Ap = Asrc[ph];
    const float* Wp = Wsrc[ph];
    for (int kt = 0; kt < KDIM / BK; ++kt) {
      const int k0 = kt * BK;
      // load fp32 tile into registers (8 float4 each for A and B per thread)
      float4 areg[8], breg[8];
      #pragma unroll
      for (int q = 0; q < 8; ++q) {
        int chunk = q * 256 + tid;          // float4 id in [0,2048)
        int row = chunk >> 4, kc = chunk & 15;
        areg[q] = *(const float4*)(Ap + (size_t)(m0 + row) * KDIM + k0 + kc * 4);
        int wrow = (row & 3) * HID + h0 + (row >> 2);   // gate*2048 + h
        breg[q] = *(const float4*)(Wp + (size_t)wrow * KDIM + k0 + kc * 4);
      }
      __syncthreads();   // previous tile's ds_reads done before overwrite
      #pragma unroll
      for (int q = 0; q < 8; ++q) {
        int chunk = q * 256 + tid;
        short4v a4 = { bf16cvt(areg[q].x), bf16cvt(areg[q].y),
                       bf16cvt(areg[q].z), bf16cvt(areg[q].w) };
        short4v b4 = { bf16cvt(breg[q].x), bf16cvt(breg[q].y),
                       bf16cvt(breg[q].z), bf16cvt(breg[q].w) };
        *(short4v*)((char*)A_lds + (size_t)chunk * 8) = a4;
        *(short4v*)((char*)B_lds + (size_t)chunk * 8) = b4;
      }
      __syncthreads();
      #pragma unroll
      for (int ks = 0; ks < 2; ++ks) {
        short8 af[4], bfv[4];
        #pragma unroll
        for (int t = 0; t < 4; ++t)
          af[t] = *(const short8*)&A_lds[(wm * 64 + t * 16 + ln) * BK + ks * 32 + quad * 8];
        #pragma unroll
        for (int t = 0; t < 4; ++t)
          bfv[t] = *(const short8*)&B_lds[(wn * 64 + t * 16 + ln) * BK + ks * 32 + quad * 8];
        #pragma unroll
        for (int tm = 0; tm < 4; ++tm)
          #pragma unroll
          for (int tn = 0; tn < 4; ++tn)
            acc[tm][tn] = __builtin_amdgcn_mfma_f32_16x16x32_bf16(
                af[tm], bfv[tn], acc[tm][tn], 0, 0, 0);
      }
    }
  }

  // ---- epilogue: C/D layout col = lane&15 (c), row = quad*4 + reg ----
  const int g = lane & 3;    // gate of this lane
  float biasv[4];
  int   hgs[4];
  #pragma unroll
  for (int tn = 0; tn < 4; ++tn) {
    int c  = wn * 64 + tn * 16 + ln;
    int hg = h0 + (c >> 2);
    hgs[tn] = hg;
    int j = g * HID + hg;
    biasv[tn] = bx[j] + bh[j];
  }
  #pragma unroll
  for (int tm = 0; tm < 4; ++tm) {
    #pragma unroll
    for (int r = 0; r < 4; ++r) {
      int mrow = m0 + wm * 64 + tm * 16 + quad * 4 + r;
      #pragma unroll
      for (int tn = 0; tn < 4; ++tn) {
        float v   = acc[tm][tn][r] + biasv[tn];
        float act = (g == 2) ? tanhx(v) : sigm(v);
        // butterfly: gather all 4 gate values for this (mrow, h)
        float y1 = __shfl_xor(act, 1);
        float y2 = __shfl_xor(act, 2);
        float y3 = __shfl_xor(act, 3);
        float ft = (g == 0) ? act : ((g == 1) ? y1 : ((g == 2) ? y2 : y3));
        float it = (g == 1) ? act : ((g == 0) ? y1 : ((g == 3) ? y2 : y3));
        float gt = (g == 2) ? act : ((g == 3) ? y1 : ((g == 0) ? y2 : y3));
        float ot = (g == 3) ? act : ((g == 2) ? y1 : ((g == 1) ? y2 : y3));
        if (g < 2) {
          size_t off = (size_t)mrow * HID + hgs[tn];
          float cxv = Cx[off];
          float cyv = ft * cxv + it * gt;
          if (g == 0) Hy[off] = ot * tanhx(cyv);
          else        Cy[off] = cyv;
        }
      }
    }
  }
}

extern "C" void kernel_launch(void* const* d_in, const int* in_sizes, int n_in,
                              void* d_out, int out_size, void* d_ws, size_t ws_size,
                              hipStream_t stream) {
  const float* X  = (const float*)d_in[0];
  const float* Hx = (const float*)d_in[1];
  const float* Cx = (const float*)d_in[2];
  const float* Wx = (const float*)d_in[3];
  const float* bx = (const float*)d_in[4];
  const float* Wh = (const float*)d_in[5];
  const float* bh = (const float*)d_in[6];
  float*       Hy = (float*)d_out;
  float*       Cy = Hy + (size_t)BATCH * HID;

  dim3 grid(HID / 32, BATCH / BM, 1);   // 64 x 32 = 2048 blocks
  dim3 block(256, 1, 1);
  lstm_cell_kernel<<<grid, block, 0, stream>>>(X, Hx, Cx, Wx, bx, Wh, bh, Hy, Cy);
}

// Round 4
// 778.675 us; speedup vs baseline: 2.3566x; 2.3566x over previous
//
#include <hip/hip_runtime.h>
#include <hip/hip_bf16.h>

// LSTM cell: gates = X @ Wx^T + Hx @ Wh^T + (bx + bh); f,i,g,o = split(gates)
// cy = sigmoid(f)*cx + sigmoid(i)*tanh(g); hy = sigmoid(o)*tanh(cy)
// Storage fp32; compute bf16 MFMA (checker bf16-tolerant, passed R2 @ 0.031).
//
// R3: (a) LDS row stride 72 shorts (144B): bank skew 4/row -> conflict-free
//     fragment reads (was 2x serialized, 1e8 conflict cycles);
//     (b) flattened 64-iter K loop with register prefetch of tile t+1 issued
//     AFTER the staging barrier and BEFORE the MFMA burst, so vmcnt drain at
//     the next barrier overlaps 32 MFMAs instead of stalling cold;
//     (c) packed bf16 conversion; (d) grid: consecutive blocks share W tile.

#define BATCH 4096
#define HID   2048
#define KDIM  2048
#define BM    128
#define BK    64
#define LDK   72   // padded LDS row stride in shorts (144B, 16B-aligned)

typedef __attribute__((ext_vector_type(8))) short  short8;
typedef __attribute__((ext_vector_type(4))) float  f32x4;

__device__ __forceinline__ float sigm(float x)  { return 1.f / (1.f + __expf(-x)); }
__device__ __forceinline__ float tanhx(float x) { return 2.f / (1.f + __expf(-2.f * x)) - 1.f; }

__device__ __forceinline__ uint2 pk_bf16x4(float4 v) {
  __hip_bfloat162 lo = __float22bfloat162_rn(make_float2(v.x, v.y));
  __hip_bfloat162 hi = __float22bfloat162_rn(make_float2(v.z, v.w));
  uint2 r;
  r.x = *(unsigned*)&lo;
  r.y = *(unsigned*)&hi;
  return r;
}

__global__ __launch_bounds__(256) void lstm_cell_kernel(
    const float* __restrict__ X, const float* __restrict__ Hx,
    const float* __restrict__ Cx,
    const float* __restrict__ Wx, const float* __restrict__ bx,
    const float* __restrict__ Wh, const float* __restrict__ bh,
    float* __restrict__ Hy, float* __restrict__ Cy)
{
  __shared__ __align__(16) short A_lds[BM * LDK];   // [m_local][k] padded
  __shared__ __align__(16) short B_lds[BM * LDK];   // [c][k]       padded

  const int tid  = threadIdx.x;
  const int wv   = tid >> 6;         // wave 0..3
  const int lane = tid & 63;
  const int quad = lane >> 4;
  const int ln   = lane & 15;
  const int wm   = wv >> 1;          // 2x2 wave grid
  const int wn   = wv & 1;
  const int m0   = blockIdx.x * BM;  // 32 m-tiles (fastest -> share W tile)
  const int h0   = blockIdx.y * 32;  // 64 h-tiles

  f32x4 acc[4][4];
  #pragma unroll
  for (int a = 0; a < 4; ++a)
    #pragma unroll
    for (int b = 0; b < 4; ++b)
      acc[a][b] = (f32x4){0.f, 0.f, 0.f, 0.f};

  // per-thread staging geometry: chunk = q*256 + tid; row = q*16 + (tid>>4),
  // kc = tid&15 (constant across q)
  const int rA  = tid >> 4;
  const int kc4 = (tid & 15) * 4;     // float offset within the 64-wide k tile
  size_t aoff[8], boff[8];
  int    lrow[8];
  #pragma unroll
  for (int q = 0; q < 8; ++q) {
    int row  = q * 16 + rA;
    lrow[q]  = row;
    aoff[q]  = (size_t)(m0 + row) * KDIM + kc4;
    int wrow = (row & 3) * HID + h0 + (row >> 2);   // gate*2048 + h
    boff[q]  = (size_t)wrow * KDIM + kc4;
  }

  const int NT = 2 * (KDIM / BK);   // 64 total k-tiles across both phases
  float4 areg[8], breg[8];
  // prefetch t = 0
  #pragma unroll
  for (int q = 0; q < 8; ++q) {
    areg[q] = *(const float4*)(X  + aoff[q]);
    breg[q] = *(const float4*)(Wx + boff[q]);
  }

  for (int t = 0; t < NT; ++t) {
    __syncthreads();   // previous tile's ds_reads done before overwrite
    #pragma unroll
    for (int q = 0; q < 8; ++q) {
      *(uint2*)&A_lds[lrow[q] * LDK + kc4] = pk_bf16x4(areg[q]);
      *(uint2*)&B_lds[lrow[q] * LDK + kc4] = pk_bf16x4(breg[q]);
    }
    __syncthreads();
    // prefetch t+1 BEFORE the MFMA burst: vmcnt drain at next barrier
    // then overlaps the 32 MFMAs below
    if (t + 1 < NT) {
      const float* Ap = (t + 1 < 32) ? X  : Hx;
      const float* Wp = (t + 1 < 32) ? Wx : Wh;
      const int k0 = ((t + 1) & 31) * BK;
      #pragma unroll
      for (int q = 0; q < 8; ++q) {
        areg[q] = *(const float4*)(Ap + aoff[q] + k0);
        breg[q] = *(const float4*)(Wp + boff[q] + k0);
      }
    }
    #pragma unroll
    for (int ks = 0; ks < 2; ++ks) {
      short8 af[4], bfv[4];
      #pragma unroll
      for (int u = 0; u < 4; ++u)
        af[u] = *(const short8*)&A_lds[(wm * 64 + u * 16 + ln) * LDK + ks * 32 + quad * 8];
      #pragma unroll
      for (int u = 0; u < 4; ++u)
        bfv[u] = *(const short8*)&B_lds[(wn * 64 + u * 16 + ln) * LDK + ks * 32 + quad * 8];
      #pragma unroll
      for (int tm = 0; tm < 4; ++tm)
        #pragma unroll
        for (int tn = 0; tn < 4; ++tn)
          acc[tm][tn] = __builtin_amdgcn_mfma_f32_16x16x32_bf16(
              af[tm], bfv[tn], acc[tm][tn], 0, 0, 0);
    }
  }

  // ---- epilogue: C/D layout col = lane&15 (c), row = quad*4 + reg ----
  const int g = lane & 3;    // gate of this lane
  float biasv[4];
  int   hgs[4];
  #pragma unroll
  for (int tn = 0; tn < 4; ++tn) {
    int c  = wn * 64 + tn * 16 + ln;
    int hg = h0 + (c >> 2);
    hgs[tn] = hg;
    int j = g * HID + hg;
    biasv[tn] = bx[j] + bh[j];
  }
  #pragma unroll
  for (int tm = 0; tm < 4; ++tm) {
    #pragma unroll
    for (int r = 0; r < 4; ++r) {
      int mrow = m0 + wm * 64 + tm * 16 + quad * 4 + r;
      #pragma unroll
      for (int tn = 0; tn < 4; ++tn) {
        float v   = acc[tm][tn][r] + biasv[tn];
        float act = (g == 2) ? tanhx(v) : sigm(v);
        float y1 = __shfl_xor(act, 1);
        float y2 = __shfl_xor(act, 2);
        float y3 = __shfl_xor(act, 3);
        float ft = (g == 0) ? act : ((g == 1) ? y1 : ((g == 2) ? y2 : y3));
        float it = (g == 1) ? act : ((g == 0) ? y1 : ((g == 3) ? y2 : y3));
        float gt = (g == 2) ? act : ((g == 3) ? y1 : ((g == 0) ? y2 : y3));
        float ot = (g == 3) ? act : ((g == 2) ? y1 : ((g == 1) ? y2 : y3));
        if (g < 2) {
          size_t off = (size_t)mrow * HID + hgs[tn];
          float cxv = Cx[off];
          float cyv = ft * cxv + it * gt;
          if (g == 0) Hy[off] = ot * tanhx(cyv);
          else        Cy[off] = cyv;
        }
      }
    }
  }
}

extern "C" void kernel_launch(void* const* d_in, const int* in_sizes, int n_in,
                              void* d_out, int out_size, void* d_ws, size_t ws_size,
                              hipStream_t stream) {
  const float* X  = (const float*)d_in[0];
  const float* Hx = (const float*)d_in[1];
  const float* Cx = (const float*)d_in[2];
  const float* Wx = (const float*)d_in[3];
  const float* bx = (const float*)d_in[4];
  const float* Wh = (const float*)d_in[5];
  const float* bh = (const float*)d_in[6];
  float*       Hy = (float*)d_out;
  float*       Cy = Hy + (size_t)BATCH * HID;

  dim3 grid(BATCH / BM, HID / 32, 1);   // 32 x 64; x fastest -> W-tile reuse
  dim3 block(256, 1, 1);
  lstm_cell_kernel<<<grid, block, 0, stream>>>(X, Hx, Cx, Wx, bx, Wh, bh, Hy, Cy);
}